// Round 3
// baseline (393.472 us; speedup 1.0000x reference)
//
#include <hip/hip_runtime.h>
#include <math.h>

#define B_ 256
#define L_ 50
#define H_ 128
#define N_ 100000
#define K_ 256  // 2H
#define NREP 64  // row-sum atomic replicas

typedef __attribute__((ext_vector_type(8))) short short8;   // 8 bf16 = 4 VGPR
typedef __attribute__((ext_vector_type(4))) float f32x4;

__device__ inline short f2bf(float x) {
  union { float f; unsigned u; } v; v.f = x;
  unsigned r = (v.u + 0x7fff + ((v.u >> 16) & 1)) >> 16;
  return (short)r;
}
__device__ inline float bf2f(short h) {
  union { unsigned u; float f; } v; v.u = ((unsigned)(unsigned short)h) << 16;
  return v.f;
}

// ---------------- Kernel A: attention + feat (bf16 hi/lo split, [B][K] layout) ----------------
__global__ __launch_bounds__(256)
void attn_feat_kernel(const float* __restrict__ am, const float* __restrict__ lm,
    const float* __restrict__ Ue_w, const float* __restrict__ Ue_b,
    const float* __restrict__ We_w, const float* __restrict__ We_b,
    const float* __restrict__ Ve_w, const float* __restrict__ Ve_b,
    const unsigned char* __restrict__ mask,
    short* __restrict__ feat_hi, short* __restrict__ feat_lo,
    float* __restrict__ sums_rep)
{
  const int b = blockIdx.x;
  const int t = threadIdx.x;  // 0..255
  __shared__ float UeS[H_ * H_];     // 64 KB, [h][k]
  __shared__ float amS[L_][H_];      // 25 KB
  __shared__ float lmS[H_], qS[H_];
  __shared__ float attnS[64];
  __shared__ float redW[4][32];      // per-wave score partials

  // zero this block's slice of the replicated row-sum accumulators (ws is poisoned)
  if (t < 64) sums_rep[b * 64 + t] = 0.0f;

  for (int i = t; i < H_ * H_ / 4; i += 256)
    ((float4*)UeS)[i] = ((const float4*)Ue_w)[i];
  for (int i = t; i < L_ * H_ / 4; i += 256)
    ((float4*)amS)[i] = ((const float4*)(am + (size_t)b * L_ * H_))[i];
  if (t < H_) lmS[t] = lm[b * H_ + t];
  __syncthreads();

  if (t < H_) {
    float q = We_b[t];
    #pragma unroll 8
    for (int h = 0; h < H_; ++h) q += lmS[h] * We_w[h * H_ + t];
    qS[t] = q;
  }
  __syncthreads();

  // scores: barrier-free main loop — wave-local reductions only
  const int k = t & 127, half = t >> 7, wv = t >> 6, lk = t & 63;
  const float ve  = Ve_w[k];
  const float ueb = Ue_b[k];
  const float veb = Ve_b[0];
  for (int li = 0; li < 25; ++li) {
    const int l = half * 25 + li;
    float a = ueb;
    #pragma unroll 8
    for (int h = 0; h < H_; ++h) a = fmaf(amS[l][h], UeS[h * H_ + k], a);
    float v = tanhf(a + qS[k]) * ve;
    #pragma unroll
    for (int off = 32; off > 0; off >>= 1) v += __shfl_down(v, off, 64);
    if (lk == 0) redW[wv][li] = v;
  }
  __syncthreads();
  if (t < 50) {
    const int hf = t / 25, li = t - hf * 25;
    attnS[t] = redW[hf * 2][li] + redW[hf * 2 + 1][li] + veb;
  }
  __syncthreads();

  if (t < 64) {
    float s = (t < L_) ? attnS[t] : -3.0e38f;
    if (t < L_ && mask[b * L_ + t]) s = -1.0e9f;
    float m = s;
    #pragma unroll
    for (int off = 32; off > 0; off >>= 1) m = fmaxf(m, __shfl_xor(m, off));
    float e = (t < L_) ? __expf(s - m) : 0.0f;
    float tot = e;
    #pragma unroll
    for (int off = 32; off > 0; off >>= 1) tot += __shfl_xor(tot, off);
    if (t < L_) attnS[t] = e / tot;
  }
  __syncthreads();

  if (t < H_) {
    float c = 0.0f;
    #pragma unroll
    for (int l = 0; l < L_; ++l) c = fmaf(attnS[l], amS[l][t], c);
    short h1 = f2bf(c);
    feat_hi[b * K_ + t] = h1;
    feat_lo[b * K_ + t] = f2bf(c - bf2f(h1));
    float lv = lmS[t];
    short h2 = f2bf(lv);
    feat_hi[b * K_ + H_ + t] = h2;
    feat_lo[b * K_ + H_ + t] = f2bf(lv - bf2f(h2));
  }
}

// ---------------- Kernel B: logits = feat @ Wexp via MFMA bf16x3 ----------------
// Barrier-free, LDS-free, transposed-fragment GEMM. We compute D^T tiles:
//   A' = Wexp^T fragments: lane(ln,quad) loads Wexp[k=quad*8+j][n0+mt*16+ln]
//        (64-B coalesced segments), packed in-reg to bf16 hi(trunc)/lo(RTNE).
//   B' = feat fragments: direct short8 loads (already bf16 hi/lo in memory).
// No __syncthreads anywhere: waves free-run, so stalls never gang-block.
// W regs are double-buffered; consuming W(s) waits only past the younger
// W(s+1) prefetch (vmcnt ordering), so the ~900-cyc HBM latency stays hidden.
// D^T layout gives float4 epilogue stores and one row-sum atomic per lane.
#define TN 64

__global__ __launch_bounds__(256)
void logits_mfma_kernel(const short* __restrict__ feat_hi, const short* __restrict__ feat_lo,
                        const float* __restrict__ Wexp, float* __restrict__ out,
                        float* __restrict__ sums_rep)
{
  const int t = threadIdx.x;
  const int w = t >> 6;              // wave -> rows w*64..w*64+63
  const int lane = t & 63;
  const int ln = lane & 15, quad = lane >> 4;
  const int n0 = blockIdx.x * TN;
  const bool tail = (n0 + TN > N_);

  // per-mt output column (lane part) + tail clamp/mask
  int coff[4];
  float msk[4];
  #pragma unroll
  for (int mt = 0; mt < 4; ++mt) {
    int c = n0 + mt * 16 + ln;
    msk[mt] = (c < N_) ? 1.0f : 0.0f;
    coff[mt] = (c < N_) ? c : (N_ - 1);
  }

  // feat base: row w*64 + ln (+ nt*16 rows), k-offset quad*8 (+ s*32)
  const short* fh0 = feat_hi + ((size_t)(w * 64 + ln)) * K_ + quad * 8;
  const short* fl0 = feat_lo + ((size_t)(w * 64 + ln)) * K_ + quad * 8;

  f32x4 acc[4][4];   // [mt][nt]
  #pragma unroll
  for (int i = 0; i < 4; ++i)
    #pragma unroll
    for (int j = 0; j < 4; ++j) acc[i][j] = (f32x4)(0.0f);

  float wreg[2][32];   // [buf][mt*8+j] fp32 W stage, double-buffered

  // issue 32 coalesced W loads for k-step s_ into buffer bi
  #define LOADW(bi, s_)                                                        \
    do {                                                                       \
      const float* gp = Wexp + (size_t)((s_) * 32 + quad * 8) * N_;            \
      _Pragma("unroll")                                                        \
      for (int mt = 0; mt < 4; ++mt)                                           \
        _Pragma("unroll")                                                      \
        for (int j = 0; j < 8; ++j)                                            \
          wreg[bi][mt * 8 + j] = gp[(size_t)j * N_ + coff[mt]];                \
    } while (0)

  // one K=32 MFMA step: load feat frags, pack W(bi) -> bf16 hi/lo, 48 MFMA
  #define STEP(s_, bi)                                                         \
    do {                                                                       \
      short8 fbh[4], fbl[4];                                                   \
      _Pragma("unroll")                                                        \
      for (int nt = 0; nt < 4; ++nt) {                                         \
        fbh[nt] = *(const short8*)(fh0 + (size_t)nt * 16 * K_ + (s_) * 32);    \
        fbl[nt] = *(const short8*)(fl0 + (size_t)nt * 16 * K_ + (s_) * 32);    \
      }                                                                        \
      short8 wa_h[4], wa_l[4];                                                 \
      _Pragma("unroll")                                                        \
      for (int mt = 0; mt < 4; ++mt) {                                         \
        _Pragma("unroll")                                                      \
        for (int j = 0; j < 8; ++j) {                                          \
          float f = wreg[bi][mt * 8 + j];                                      \
          if (tail) f *= msk[mt];                                              \
          union { float f; unsigned u; } v_; v_.f = f;                         \
          union { unsigned u; float f; } h_; h_.u = v_.u & 0xffff0000u;        \
          wa_h[mt][j] = (short)(v_.u >> 16);                                   \
          wa_l[mt][j] = f2bf(f - h_.f);                                        \
        }                                                                      \
      }                                                                        \
      _Pragma("unroll")                                                        \
      for (int mt = 0; mt < 4; ++mt)                                           \
        _Pragma("unroll")                                                      \
        for (int nt = 0; nt < 4; ++nt) {                                       \
          acc[mt][nt] = __builtin_amdgcn_mfma_f32_16x16x32_bf16(wa_h[mt], fbh[nt], acc[mt][nt], 0, 0, 0); \
          acc[mt][nt] = __builtin_amdgcn_mfma_f32_16x16x32_bf16(wa_l[mt], fbh[nt], acc[mt][nt], 0, 0, 0); \
          acc[mt][nt] = __builtin_amdgcn_mfma_f32_16x16x32_bf16(wa_h[mt], fbl[nt], acc[mt][nt], 0, 0, 0); \
        }                                                                      \
    } while (0)

  LOADW(0, 0);
  #pragma unroll
  for (int s = 0; s < 8; ++s) {
    if (s < 7) LOADW((s + 1) & 1, s + 1);   // prefetch next W (stays in flight)
    STEP(s, s & 1);
  }

  // epilogue: exp, float4 stores, per-row sums. D^T layout:
  //   out row = w*64 + nt*16 + ln ; out col = n0 + mt*16 + quad*4 + r
  float rs[4] = {0.0f, 0.0f, 0.0f, 0.0f};   // per-nt row partial sums
  #pragma unroll
  for (int mt = 0; mt < 4; ++mt) {
    const int c0 = n0 + mt * 16 + quad * 4;
    const bool ok = c0 < N_;                // N_ % 4 == 0: float4 never straddles
    #pragma unroll
    for (int nt = 0; nt < 4; ++nt) {
      float4 ev;
      float s4;
      {
        const float e0 = __expf(acc[mt][nt][0]);
        const float e1 = __expf(acc[mt][nt][1]);
        const float e2 = __expf(acc[mt][nt][2]);
        const float e3 = __expf(acc[mt][nt][3]);
        ev.x = e0; ev.y = e1; ev.z = e2; ev.w = e3;
        s4 = (e0 + e1) + (e2 + e3);
      }
      if (ok) {
        *(float4*)(out + (size_t)(w * 64 + nt * 16 + ln) * N_ + c0) = ev;
        rs[nt] += s4;
      }
    }
  }
  // reduce across quads: after xor16+xor32 every lane holds the full sum for (nt, ln)
  #pragma unroll
  for (int nt = 0; nt < 4; ++nt) {
    rs[nt] += __shfl_xor(rs[nt], 16, 64);
    rs[nt] += __shfl_xor(rs[nt], 32, 64);
  }
  // lane (ln, quad) owns row w*64 + quad*16 + ln = w*64 + lane
  const float mine = (quad == 0) ? rs[0] : (quad == 1) ? rs[1] : (quad == 2) ? rs[2] : rs[3];
  atomicAdd(&sums_rep[(size_t)(blockIdx.x & (NREP - 1)) * 256 + w * 64 + lane], mine);
}

// ---------------- Kernel B2: fold the 64 replicas into sums ----------------
__global__ __launch_bounds__(256)
void reduce_sums_kernel(const float* __restrict__ sums_rep, float* __restrict__ sums)
{
  const int b = threadIdx.x;   // one thread per row, single block
  float s = 0.0f;
  #pragma unroll
  for (int r = 0; r < NREP; ++r) s += sums_rep[r * 256 + b];
  sums[b] = s;
}

// ---------------- Kernel C: explore mask ----------------
__global__ __launch_bounds__(256)
void mask_kernel(const int* __restrict__ seq, float* __restrict__ out, float* __restrict__ sums)
{
  int idx = blockIdx.x * 256 + threadIdx.x;   // B*L = 12800
  if (idx >= B_ * L_) return;
  int b = idx / L_;
  int item = seq[idx];
  if (item > 0) {
    float old = atomicExch(&out[(size_t)b * N_ + item], 0.0f);
    if (old != 0.0f) atomicAdd(&sums[b], -old);   // 256 addresses, <=50 ops each: fine
  }
}

// ---------------- Kernel D: normalize (2D grid, no div, 4 float4/thread) ----------------
#define NV4 (N_ / 4)   // 25000 float4 per row
__global__ __launch_bounds__(256)
void norm_kernel(float* __restrict__ out, const float* __restrict__ sums)
{
  const int b = blockIdx.y;
  const float inv = 1.0f / sums[b];
  float4* row = (float4*)(out + (size_t)b * N_);
  const int i0 = blockIdx.x * (256 * 4) + threadIdx.x;
  #pragma unroll
  for (int u = 0; u < 4; ++u) {
    const int i = i0 + u * 256;
    if (i < NV4) {
      float4 v = row[i];
      v.x *= inv; v.y *= inv; v.z *= inv; v.w *= inv;
      row[i] = v;
    }
  }
}

extern "C" void kernel_launch(void* const* d_in, const int* in_sizes, int n_in,
                              void* d_out, int out_size, void* d_ws, size_t ws_size,
                              hipStream_t stream)
{
  const float* am   = (const float*)d_in[0];
  const float* lm   = (const float*)d_in[1];
  const int*   seq  = (const int*)d_in[2];
  const unsigned char* mask = (const unsigned char*)d_in[3];
  const float* Ue_w = (const float*)d_in[4];
  const float* Ue_b = (const float*)d_in[5];
  const float* We_w = (const float*)d_in[6];
  const float* We_b = (const float*)d_in[7];
  const float* Ve_w = (const float*)d_in[8];
  const float* Ve_b = (const float*)d_in[9];
  const float* Wexp = (const float*)d_in[10];
  float* out = (float*)d_out;

  short* feat_hi  = (short*)d_ws;                     // 128 KB
  short* feat_lo  = feat_hi + B_ * K_;                // 128 KB
  float* sums_rep = (float*)(feat_lo + B_ * K_);      // 64*256 floats = 64 KB
  float* sums     = sums_rep + NREP * 256;            // 256 floats

  attn_feat_kernel<<<B_, 256, 0, stream>>>(am, lm, Ue_w, Ue_b, We_w, We_b,
                                           Ve_w, Ve_b, mask, feat_hi, feat_lo, sums_rep);
  logits_mfma_kernel<<<(N_ + TN - 1) / TN, 256, 0, stream>>>(feat_hi, feat_lo, Wexp, out, sums_rep);
  reduce_sums_kernel<<<1, 256, 0, stream>>>(sums_rep, sums);
  mask_kernel<<<(B_ * L_ + 255) / 256, 256, 0, stream>>>(seq, out, sums);
  dim3 gN((NV4 + 256 * 4 - 1) / (256 * 4), B_);
  norm_kernel<<<gN, 256, 0, stream>>>(out, sums);
}

// Round 5
// 365.786 us; speedup vs baseline: 1.0757x; 1.0757x over previous
//
#include <hip/hip_runtime.h>
#include <math.h>

#define B_ 256
#define L_ 50
#define H_ 128
#define N_ 100000
#define K_ 256  // 2H
#define NREP 64  // row-sum atomic replicas

typedef __attribute__((ext_vector_type(8))) short short8;   // 8 bf16 = 4 VGPR
typedef __attribute__((ext_vector_type(4))) float f32x4;

__device__ inline short f2bf(float x) {
  union { float f; unsigned u; } v; v.f = x;
  unsigned r = (v.u + 0x7fff + ((v.u >> 16) & 1)) >> 16;
  return (short)r;
}
__device__ inline float bf2f(short h) {
  union { unsigned u; float f; } v; v.u = ((unsigned)(unsigned short)h) << 16;
  return v.f;
}

// ---------------- Kernel A: attention + feat (bf16 hi/lo split, [B][K] layout) ----------------
__global__ __launch_bounds__(256)
void attn_feat_kernel(const float* __restrict__ am, const float* __restrict__ lm,
    const float* __restrict__ Ue_w, const float* __restrict__ Ue_b,
    const float* __restrict__ We_w, const float* __restrict__ We_b,
    const float* __restrict__ Ve_w, const float* __restrict__ Ve_b,
    const unsigned char* __restrict__ mask,
    short* __restrict__ feat_hi, short* __restrict__ feat_lo,
    float* __restrict__ sums_rep)
{
  const int b = blockIdx.x;
  const int t = threadIdx.x;  // 0..255
  __shared__ float UeS[H_ * H_];     // 64 KB, [h][k]
  __shared__ float amS[L_][H_];      // 25 KB
  __shared__ float lmS[H_], qS[H_];
  __shared__ float attnS[64];
  __shared__ float redW[4][32];      // per-wave score partials

  // zero this block's slice of the replicated row-sum accumulators (ws is poisoned)
  if (t < 64) sums_rep[b * 64 + t] = 0.0f;

  for (int i = t; i < H_ * H_ / 4; i += 256)
    ((float4*)UeS)[i] = ((const float4*)Ue_w)[i];
  for (int i = t; i < L_ * H_ / 4; i += 256)
    ((float4*)amS)[i] = ((const float4*)(am + (size_t)b * L_ * H_))[i];
  if (t < H_) lmS[t] = lm[b * H_ + t];
  __syncthreads();

  if (t < H_) {
    float q = We_b[t];
    #pragma unroll 8
    for (int h = 0; h < H_; ++h) q += lmS[h] * We_w[h * H_ + t];
    qS[t] = q;
  }
  __syncthreads();

  // scores: barrier-free main loop — wave-local reductions only
  const int k = t & 127, half = t >> 7, wv = t >> 6, lk = t & 63;
  const float ve  = Ve_w[k];
  const float ueb = Ue_b[k];
  const float veb = Ve_b[0];
  for (int li = 0; li < 25; ++li) {
    const int l = half * 25 + li;
    float a = ueb;
    #pragma unroll 8
    for (int h = 0; h < H_; ++h) a = fmaf(amS[l][h], UeS[h * H_ + k], a);
    float v = tanhf(a + qS[k]) * ve;
    #pragma unroll
    for (int off = 32; off > 0; off >>= 1) v += __shfl_down(v, off, 64);
    if (lk == 0) redW[wv][li] = v;
  }
  __syncthreads();
  if (t < 50) {
    const int hf = t / 25, li = t - hf * 25;
    attnS[t] = redW[hf * 2][li] + redW[hf * 2 + 1][li] + veb;
  }
  __syncthreads();

  if (t < 64) {
    float s = (t < L_) ? attnS[t] : -3.0e38f;
    if (t < L_ && mask[b * L_ + t]) s = -1.0e9f;
    float m = s;
    #pragma unroll
    for (int off = 32; off > 0; off >>= 1) m = fmaxf(m, __shfl_xor(m, off));
    float e = (t < L_) ? __expf(s - m) : 0.0f;
    float tot = e;
    #pragma unroll
    for (int off = 32; off > 0; off >>= 1) tot += __shfl_xor(tot, off);
    if (t < L_) attnS[t] = e / tot;
  }
  __syncthreads();

  if (t < H_) {
    float c = 0.0f;
    #pragma unroll
    for (int l = 0; l < L_; ++l) c = fmaf(attnS[l], amS[l][t], c);
    short h1 = f2bf(c);
    feat_hi[b * K_ + t] = h1;
    feat_lo[b * K_ + t] = f2bf(c - bf2f(h1));
    float lv = lmS[t];
    short h2 = f2bf(lv);
    feat_hi[b * K_ + H_ + t] = h2;
    feat_lo[b * K_ + H_ + t] = f2bf(lv - bf2f(h2));
  }
}

// ---------------- Kernel B: logits = feat @ Wexp via MFMA bf16x3 ----------------
// STATIONARY-A design for the skinny-M shape: block = 512 thr (8 waves), owns a
// 64-row M-slice x 512-col N-slice. The feat hi/lo slice (64 KB) is staged into
// LDS ONCE (XOR-swizzled rows: byte ^= (row&7)<<4 on both write and read), one
// barrier, then waves free-run: each wave owns a DISTINCT 64-col subtile (no W
// duplication), streams Wexp via a 2-deep register double-buffer, reads its
// A-fragments as conflict-free ds_read_b128 (~12cy instead of ~600cy global),
// packs W once per element, 48 MFMA per k-step. Epilogue: one atomic per lane.
#define TNW 64                      // cols per wave
#define WAVES 8
#define TNB (TNW * WAVES)           // 512 cols per block
#define MBR 64                      // rows per block
#define NBX ((N_ + TNB - 1) / TNB)  // 196

__global__ __launch_bounds__(512, 2)
void logits_mfma_kernel(const short* __restrict__ feat_hi, const short* __restrict__ feat_lo,
                        const float* __restrict__ Wexp, float* __restrict__ out,
                        float* __restrict__ sums_rep)
{
  __shared__ __align__(16) short fhS[MBR * K_];   // 32 KB (swizzled row layout)
  __shared__ __align__(16) short flS[MBR * K_];   // 32 KB

  const int t = threadIdx.x;
  const int w = t >> 6, lane = t & 63, ln = lane & 15, quad = lane >> 4;
  const int m0 = blockIdx.y * MBR;
  const int n0w = blockIdx.x * TNB + w * TNW;
  const bool tail = (n0w + TNW > N_);

  // per-nt column (lane part), clamped + mask
  int coff[4]; float cmask[4];
  #pragma unroll
  for (int nt = 0; nt < 4; ++nt) {
    const int c = n0w + nt * 16 + ln;
    cmask[nt] = (c < N_) ? 1.0f : 0.0f;
    coff[nt] = (c < N_) ? c : (N_ - 1);
  }

  float wreg[2][32];   // [buf][nt*8+j] fp32 W stage, double-buffered

  #define LOADW(bi, s_)                                                        \
    do {                                                                       \
      const float* gp = Wexp + (size_t)((s_) * 32 + quad * 8) * N_;            \
      _Pragma("unroll")                                                        \
      for (int nt = 0; nt < 4; ++nt)                                           \
        _Pragma("unroll")                                                      \
        for (int j = 0; j < 8; ++j)                                            \
          wreg[bi][nt * 8 + j] = gp[(size_t)j * N_ + coff[nt]];                \
    } while (0)

  // issue first W step early: HBM latency overlaps the feat staging below
  LOADW(0, 0);

  // ---- stage feat slice (rows m0..m0+63, all K=256, hi+lo) into LDS ----
  // 16B granule; 64 rows x 32 slots = 2048 granules per array; 4 per thread
  {
    const int slot = t & 31;
    const int row0 = t >> 5;   // 0..15
    #pragma unroll
    for (int i = 0; i < 4; ++i) {
      const int row = row0 + i * 16;
      const short8 vh = *(const short8*)(feat_hi + (size_t)(m0 + row) * K_ + slot * 8);
      const short8 vl = *(const short8*)(feat_lo + (size_t)(m0 + row) * K_ + slot * 8);
      const int byte = (row * 512 + slot * 16) ^ ((row & 7) << 4);
      *(short8*)((char*)fhS + byte) = vh;
      *(short8*)((char*)flS + byte) = vl;
    }
  }
  __syncthreads();   // only barrier in the kernel

  f32x4 acc[4][4];   // [mt][nt]
  #pragma unroll
  for (int i = 0; i < 4; ++i)
    #pragma unroll
    for (int j = 0; j < 4; ++j) acc[i][j] = (f32x4)(0.0f);

  #pragma unroll
  for (int s = 0; s < 8; ++s) {
    if (s < 7) LOADW((s + 1) & 1, s + 1);   // prefetch next W step (stays in flight)
    const int bi = s & 1;

    // pack W(s) once -> bf16 hi (trunc) / lo (RTNE residual)
    short8 bh[4], bl[4];
    #pragma unroll
    for (int nt = 0; nt < 4; ++nt) {
      #pragma unroll
      for (int j = 0; j < 8; ++j) {
        float f = wreg[bi][nt * 8 + j];
        if (tail) f *= cmask[nt];
        union { float f; unsigned u; } v_; v_.f = f;
        union { unsigned u; float f; } h_; h_.u = v_.u & 0xffff0000u;
        bh[nt][j] = (short)(v_.u >> 16);
        bl[nt][j] = f2bf(f - h_.f);
      }
    }

    // A-fragments from LDS (swizzled, conflict-light ds_read_b128)
    short8 ah[4], al[4];
    #pragma unroll
    for (int mt = 0; mt < 4; ++mt) {
      const int byte = ((mt * 16 + ln) * 512 + s * 64 + quad * 16) ^ ((ln & 7) << 4);
      ah[mt] = *(const short8*)((const char*)fhS + byte);
      al[mt] = *(const short8*)((const char*)flS + byte);
    }

    #pragma unroll
    for (int mt = 0; mt < 4; ++mt)
      #pragma unroll
      for (int nt = 0; nt < 4; ++nt) {
        acc[mt][nt] = __builtin_amdgcn_mfma_f32_16x16x32_bf16(ah[mt], bh[nt], acc[mt][nt], 0, 0, 0);
        acc[mt][nt] = __builtin_amdgcn_mfma_f32_16x16x32_bf16(ah[mt], bl[nt], acc[mt][nt], 0, 0, 0);
        acc[mt][nt] = __builtin_amdgcn_mfma_f32_16x16x32_bf16(al[mt], bh[nt], acc[mt][nt], 0, 0, 0);
      }
  }

  // epilogue: exp, predicated stores, row sums. C/D: col = ln, row = quad*4 + r
  float rs[4][4];
  #pragma unroll
  for (int mt = 0; mt < 4; ++mt)
    #pragma unroll
    for (int r_ = 0; r_ < 4; ++r_) rs[mt][r_] = 0.0f;

  #pragma unroll
  for (int mt = 0; mt < 4; ++mt) {
    #pragma unroll
    for (int nt = 0; nt < 4; ++nt) {
      const int col = n0w + nt * 16 + ln;
      #pragma unroll
      for (int r_ = 0; r_ < 4; ++r_) {
        const int row = m0 + mt * 16 + quad * 4 + r_;
        const float e = __expf(acc[mt][nt][r_]);
        if (col < N_) {
          out[(size_t)row * N_ + col] = e;
          rs[mt][r_] += e;
        }
      }
    }
  }
  // reduce over the 16 ln lanes (stays within each quad group)
  #pragma unroll
  for (int off = 8; off > 0; off >>= 1)
    #pragma unroll
    for (int mt = 0; mt < 4; ++mt)
      #pragma unroll
      for (int r_ = 0; r_ < 4; ++r_) rs[mt][r_] += __shfl_xor(rs[mt][r_], off, 64);

  // one atomic per lane: lane ln within its quad owns (mt = ln>>2, r = ln&3)
  const int my_mt = ln >> 2, my_r = ln & 3;
  const float v0_ = (my_r == 0) ? rs[0][0] : (my_r == 1) ? rs[0][1] : (my_r == 2) ? rs[0][2] : rs[0][3];
  const float v1_ = (my_r == 0) ? rs[1][0] : (my_r == 1) ? rs[1][1] : (my_r == 2) ? rs[1][2] : rs[1][3];
  const float v2_ = (my_r == 0) ? rs[2][0] : (my_r == 1) ? rs[2][1] : (my_r == 2) ? rs[2][2] : rs[2][3];
  const float v3_ = (my_r == 0) ? rs[3][0] : (my_r == 1) ? rs[3][1] : (my_r == 2) ? rs[3][2] : rs[3][3];
  const float myv = (my_mt == 0) ? v0_ : (my_mt == 1) ? v1_ : (my_mt == 2) ? v2_ : v3_;
  const int myrow = m0 + my_mt * 16 + quad * 4 + my_r;
  atomicAdd(&sums_rep[(size_t)(blockIdx.x & (NREP - 1)) * 256 + myrow], myv);
}

// ---------------- Kernel B2: fold the 64 replicas into sums ----------------
__global__ __launch_bounds__(256)
void reduce_sums_kernel(const float* __restrict__ sums_rep, float* __restrict__ sums)
{
  const int b = threadIdx.x;   // one thread per row, single block
  float s = 0.0f;
  #pragma unroll
  for (int r = 0; r < NREP; ++r) s += sums_rep[r * 256 + b];
  sums[b] = s;
}

// ---------------- Kernel C: explore mask ----------------
__global__ __launch_bounds__(256)
void mask_kernel(const int* __restrict__ seq, float* __restrict__ out, float* __restrict__ sums)
{
  int idx = blockIdx.x * 256 + threadIdx.x;   // B*L = 12800
  if (idx >= B_ * L_) return;
  int b = idx / L_;
  int item = seq[idx];
  if (item > 0) {
    float old = atomicExch(&out[(size_t)b * N_ + item], 0.0f);
    if (old != 0.0f) atomicAdd(&sums[b], -old);   // 256 addresses, <=50 ops each: fine
  }
}

// ---------------- Kernel D: normalize (2D grid, no div, 4 float4/thread) ----------------
#define NV4 (N_ / 4)   // 25000 float4 per row
__global__ __launch_bounds__(256)
void norm_kernel(float* __restrict__ out, const float* __restrict__ sums)
{
  const int b = blockIdx.y;
  const float inv = 1.0f / sums[b];
  float4* row = (float4*)(out + (size_t)b * N_);
  const int i0 = blockIdx.x * (256 * 4) + threadIdx.x;
  #pragma unroll
  for (int u = 0; u < 4; ++u) {
    const int i = i0 + u * 256;
    if (i < NV4) {
      float4 v = row[i];
      v.x *= inv; v.y *= inv; v.z *= inv; v.w *= inv;
      row[i] = v;
    }
  }
}

extern "C" void kernel_launch(void* const* d_in, const int* in_sizes, int n_in,
                              void* d_out, int out_size, void* d_ws, size_t ws_size,
                              hipStream_t stream)
{
  const float* am   = (const float*)d_in[0];
  const float* lm   = (const float*)d_in[1];
  const int*   seq  = (const int*)d_in[2];
  const unsigned char* mask = (const unsigned char*)d_in[3];
  const float* Ue_w = (const float*)d_in[4];
  const float* Ue_b = (const float*)d_in[5];
  const float* We_w = (const float*)d_in[6];
  const float* We_b = (const float*)d_in[7];
  const float* Ve_w = (const float*)d_in[8];
  const float* Ve_b = (const float*)d_in[9];
  const float* Wexp = (const float*)d_in[10];
  float* out = (float*)d_out;

  short* feat_hi  = (short*)d_ws;                     // 128 KB
  short* feat_lo  = feat_hi + B_ * K_;                // 128 KB
  float* sums_rep = (float*)(feat_lo + B_ * K_);      // 64*256 floats = 64 KB
  float* sums     = sums_rep + NREP * 256;            // 256 floats

  attn_feat_kernel<<<B_, 256, 0, stream>>>(am, lm, Ue_w, Ue_b, We_w, We_b,
                                           Ve_w, Ve_b, mask, feat_hi, feat_lo, sums_rep);
  dim3 gB(NBX, B_ / MBR);   // 196 x 4
  logits_mfma_kernel<<<gB, 512, 0, stream>>>(feat_hi, feat_lo, Wexp, out, sums_rep);
  reduce_sums_kernel<<<1, 256, 0, stream>>>(sums_rep, sums);
  mask_kernel<<<(B_ * L_ + 255) / 256, 256, 0, stream>>>(seq, out, sums);
  dim3 gN((NV4 + 256 * 4 - 1) / (256 * 4), B_);
  norm_kernel<<<gN, 256, 0, stream>>>(out, sums);
}

// Round 6
// 344.242 us; speedup vs baseline: 1.1430x; 1.0626x over previous
//
#include <hip/hip_runtime.h>
#include <math.h>

#define B_ 256
#define L_ 50
#define H_ 128
#define N_ 100000
#define K_ 256  // 2H
#define NREP 64  // row-sum atomic replicas

typedef __attribute__((ext_vector_type(8))) short short8;   // 8 bf16 = 4 VGPR
typedef __attribute__((ext_vector_type(4))) float f32x4;

__device__ inline short f2bf(float x) {
  union { float f; unsigned u; } v; v.f = x;
  unsigned r = (v.u + 0x7fff + ((v.u >> 16) & 1)) >> 16;
  return (short)r;
}
__device__ inline float bf2f(short h) {
  union { unsigned u; float f; } v; v.u = ((unsigned)(unsigned short)h) << 16;
  return v.f;
}

// ---------------- Kernel A: attention + feat (bf16 hi/lo split, [B][K] layout) ----------------
__global__ __launch_bounds__(256)
void attn_feat_kernel(const float* __restrict__ am, const float* __restrict__ lm,
    const float* __restrict__ Ue_w, const float* __restrict__ Ue_b,
    const float* __restrict__ We_w, const float* __restrict__ We_b,
    const float* __restrict__ Ve_w, const float* __restrict__ Ve_b,
    const unsigned char* __restrict__ mask,
    short* __restrict__ feat_hi, short* __restrict__ feat_lo,
    float* __restrict__ sums_rep)
{
  const int b = blockIdx.x;
  const int t = threadIdx.x;  // 0..255
  __shared__ float UeS[H_ * H_];     // 64 KB, [h][k]
  __shared__ float amS[L_][H_];      // 25 KB
  __shared__ float lmS[H_], qS[H_];
  __shared__ float attnS[64];
  __shared__ float redW[4][32];      // per-wave score partials

  // zero this block's slice of the replicated row-sum accumulators (ws is poisoned)
  if (t < 64) sums_rep[b * 64 + t] = 0.0f;

  for (int i = t; i < H_ * H_ / 4; i += 256)
    ((float4*)UeS)[i] = ((const float4*)Ue_w)[i];
  for (int i = t; i < L_ * H_ / 4; i += 256)
    ((float4*)amS)[i] = ((const float4*)(am + (size_t)b * L_ * H_))[i];
  if (t < H_) lmS[t] = lm[b * H_ + t];
  __syncthreads();

  if (t < H_) {
    float q = We_b[t];
    #pragma unroll 8
    for (int h = 0; h < H_; ++h) q += lmS[h] * We_w[h * H_ + t];
    qS[t] = q;
  }
  __syncthreads();

  // scores: barrier-free main loop — wave-local reductions only
  const int k = t & 127, half = t >> 7, wv = t >> 6, lk = t & 63;
  const float ve  = Ve_w[k];
  const float ueb = Ue_b[k];
  const float veb = Ve_b[0];
  for (int li = 0; li < 25; ++li) {
    const int l = half * 25 + li;
    float a = ueb;
    #pragma unroll 8
    for (int h = 0; h < H_; ++h) a = fmaf(amS[l][h], UeS[h * H_ + k], a);
    float v = tanhf(a + qS[k]) * ve;
    #pragma unroll
    for (int off = 32; off > 0; off >>= 1) v += __shfl_down(v, off, 64);
    if (lk == 0) redW[wv][li] = v;
  }
  __syncthreads();
  if (t < 50) {
    const int hf = t / 25, li = t - hf * 25;
    attnS[t] = redW[hf * 2][li] + redW[hf * 2 + 1][li] + veb;
  }
  __syncthreads();

  if (t < 64) {
    float s = (t < L_) ? attnS[t] : -3.0e38f;
    if (t < L_ && mask[b * L_ + t]) s = -1.0e9f;
    float m = s;
    #pragma unroll
    for (int off = 32; off > 0; off >>= 1) m = fmaxf(m, __shfl_xor(m, off));
    float e = (t < L_) ? __expf(s - m) : 0.0f;
    float tot = e;
    #pragma unroll
    for (int off = 32; off > 0; off >>= 1) tot += __shfl_xor(tot, off);
    if (t < L_) attnS[t] = e / tot;
  }
  __syncthreads();

  if (t < H_) {
    float c = 0.0f;
    #pragma unroll
    for (int l = 0; l < L_; ++l) c = fmaf(attnS[l], amS[l][t], c);
    short h1 = f2bf(c);
    feat_hi[b * K_ + t] = h1;
    feat_lo[b * K_ + t] = f2bf(c - bf2f(h1));
    float lv = lmS[t];
    short h2 = f2bf(lv);
    feat_hi[b * K_ + H_ + t] = h2;
    feat_lo[b * K_ + H_ + t] = f2bf(lv - bf2f(h2));
  }
}

// ---------------- Kernel B: logits = feat @ Wexp via MFMA bf16x3 ----------------
// STATIONARY-A (as R5) + XCD-SIBLING SWIZZLE: the 4 M-slice siblings of one
// N-column group share a 512-KB Wexp slice. 1D grid, bijective remap so the 4
// siblings' linear block ids differ by exactly 8 -> same XCD (round-robin
// assignment) -> the XCD's 4MB L2 serves 3 of the 4 W streams. Cuts HBM fetch
// ~2x and W-load latency 900->~200cy on most loads. Rest identical to R5.
#define TNW 64                      // cols per wave
#define WAVES 8
#define TNB (TNW * WAVES)           // 512 cols per block
#define MBR 64                      // rows per block
#define NBX ((N_ + TNB - 1) / TNB)  // 196
#define GRIDB (NBX * 4)             // 784

__global__ __launch_bounds__(512, 2)
void logits_mfma_kernel(const short* __restrict__ feat_hi, const short* __restrict__ feat_lo,
                        const float* __restrict__ Wexp, float* __restrict__ out,
                        float* __restrict__ sums_rep)
{
  __shared__ __align__(16) short fhS[MBR * K_];   // 32 KB (swizzled row layout)
  __shared__ __align__(16) short flS[MBR * K_];   // 32 KB

  const int t = threadIdx.x;
  const int w = t >> 6, lane = t & 63, ln = lane & 15, quad = lane >> 4;

  // XCD-sibling remap: bid -> (x, y); siblings (same x, y=0..3) differ by 8 in bid
  const int bid = blockIdx.x;
  int x, y;
  if (bid < 768) { x = (bid >> 5) * 8 + (bid & 7); y = (bid >> 3) & 3; }
  else           { const int r = bid - 768; x = 192 + (r >> 2); y = r & 3; }

  const int m0 = y * MBR;
  const int n0w = x * TNB + w * TNW;
  const bool tail = (n0w + TNW > N_);

  // per-nt column (lane part), clamped + mask
  int coff[4]; float cmask[4];
  #pragma unroll
  for (int nt = 0; nt < 4; ++nt) {
    const int c = n0w + nt * 16 + ln;
    cmask[nt] = (c < N_) ? 1.0f : 0.0f;
    coff[nt] = (c < N_) ? c : (N_ - 1);
  }

  float wreg[2][32];   // [buf][nt*8+j] fp32 W stage, double-buffered

  #define LOADW(bi, s_)                                                        \
    do {                                                                       \
      const float* gp = Wexp + (size_t)((s_) * 32 + quad * 8) * N_;            \
      _Pragma("unroll")                                                        \
      for (int nt = 0; nt < 4; ++nt)                                           \
        _Pragma("unroll")                                                      \
        for (int j = 0; j < 8; ++j)                                            \
          wreg[bi][nt * 8 + j] = gp[(size_t)j * N_ + coff[nt]];                \
    } while (0)

  // issue first W step early: HBM latency overlaps the feat staging below
  LOADW(0, 0);

  // ---- stage feat slice (rows m0..m0+63, all K=256, hi+lo) into LDS ----
  // 16B granule; 64 rows x 32 slots = 2048 granules per array; 4 per thread
  {
    const int slot = t & 31;
    const int row0 = t >> 5;   // 0..15
    #pragma unroll
    for (int i = 0; i < 4; ++i) {
      const int row = row0 + i * 16;
      const short8 vh = *(const short8*)(feat_hi + (size_t)(m0 + row) * K_ + slot * 8);
      const short8 vl = *(const short8*)(feat_lo + (size_t)(m0 + row) * K_ + slot * 8);
      const int byte = (row * 512 + slot * 16) ^ ((row & 7) << 4);
      *(short8*)((char*)fhS + byte) = vh;
      *(short8*)((char*)flS + byte) = vl;
    }
  }
  __syncthreads();   // only barrier in the kernel

  f32x4 acc[4][4];   // [mt][nt]
  #pragma unroll
  for (int i = 0; i < 4; ++i)
    #pragma unroll
    for (int j = 0; j < 4; ++j) acc[i][j] = (f32x4)(0.0f);

  #pragma unroll
  for (int s = 0; s < 8; ++s) {
    if (s < 7) LOADW((s + 1) & 1, s + 1);   // prefetch next W step (stays in flight)
    const int bi = s & 1;

    // pack W(s) once -> bf16 hi (trunc) / lo (RTNE residual)
    short8 bh[4], bl[4];
    #pragma unroll
    for (int nt = 0; nt < 4; ++nt) {
      #pragma unroll
      for (int j = 0; j < 8; ++j) {
        float f = wreg[bi][nt * 8 + j];
        if (tail) f *= cmask[nt];
        union { float f; unsigned u; } v_; v_.f = f;
        union { unsigned u; float f; } h_; h_.u = v_.u & 0xffff0000u;
        bh[nt][j] = (short)(v_.u >> 16);
        bl[nt][j] = f2bf(f - h_.f);
      }
    }

    // A-fragments from LDS (swizzled ds_read_b128)
    short8 ah[4], al[4];
    #pragma unroll
    for (int mt = 0; mt < 4; ++mt) {
      const int byte = ((mt * 16 + ln) * 512 + s * 64 + quad * 16) ^ ((ln & 7) << 4);
      ah[mt] = *(const short8*)((const char*)fhS + byte);
      al[mt] = *(const short8*)((const char*)flS + byte);
    }

    #pragma unroll
    for (int mt = 0; mt < 4; ++mt)
      #pragma unroll
      for (int nt = 0; nt < 4; ++nt) {
        acc[mt][nt] = __builtin_amdgcn_mfma_f32_16x16x32_bf16(ah[mt], bh[nt], acc[mt][nt], 0, 0, 0);
        acc[mt][nt] = __builtin_amdgcn_mfma_f32_16x16x32_bf16(ah[mt], bl[nt], acc[mt][nt], 0, 0, 0);
        acc[mt][nt] = __builtin_amdgcn_mfma_f32_16x16x32_bf16(al[mt], bh[nt], acc[mt][nt], 0, 0, 0);
      }
  }

  // epilogue: exp, predicated stores, row sums. C/D: col = ln, row = quad*4 + r
  float rs[4][4];
  #pragma unroll
  for (int mt = 0; mt < 4; ++mt)
    #pragma unroll
    for (int r_ = 0; r_ < 4; ++r_) rs[mt][r_] = 0.0f;

  #pragma unroll
  for (int mt = 0; mt < 4; ++mt) {
    #pragma unroll
    for (int nt = 0; nt < 4; ++nt) {
      const int col = n0w + nt * 16 + ln;
      #pragma unroll
      for (int r_ = 0; r_ < 4; ++r_) {
        const int row = m0 + mt * 16 + quad * 4 + r_;
        const float e = __expf(acc[mt][nt][r_]);
        if (col < N_) {
          out[(size_t)row * N_ + col] = e;
          rs[mt][r_] += e;
        }
      }
    }
  }
  // reduce over the 16 ln lanes (stays within each quad group)
  #pragma unroll
  for (int off = 8; off > 0; off >>= 1)
    #pragma unroll
    for (int mt = 0; mt < 4; ++mt)
      #pragma unroll
      for (int r_ = 0; r_ < 4; ++r_) rs[mt][r_] += __shfl_xor(rs[mt][r_], off, 64);

  // one atomic per lane: lane ln within its quad owns (mt = ln>>2, r = ln&3)
  const int my_mt = ln >> 2, my_r = ln & 3;
  const float v0_ = (my_r == 0) ? rs[0][0] : (my_r == 1) ? rs[0][1] : (my_r == 2) ? rs[0][2] : rs[0][3];
  const float v1_ = (my_r == 0) ? rs[1][0] : (my_r == 1) ? rs[1][1] : (my_r == 2) ? rs[1][2] : rs[1][3];
  const float v2_ = (my_r == 0) ? rs[2][0] : (my_r == 1) ? rs[2][1] : (my_r == 2) ? rs[2][2] : rs[2][3];
  const float v3_ = (my_r == 0) ? rs[3][0] : (my_r == 1) ? rs[3][1] : (my_r == 2) ? rs[3][2] : rs[3][3];
  const float myv = (my_mt == 0) ? v0_ : (my_mt == 1) ? v1_ : (my_mt == 2) ? v2_ : v3_;
  const int myrow = m0 + my_mt * 16 + quad * 4 + my_r;
  atomicAdd(&sums_rep[(size_t)(x & (NREP - 1)) * 256 + myrow], myv);
}

// ---------------- Kernel B2+C fused: fold replicas + explore mask ----------------
// One block per batch row b (64 threads = 1 wave): lane t sums replica t for
// row b, wave-reduce; lanes 0..49 zero this row's seq items (atomicExch dedups
// repeats) and the zeroed mass is wave-reduced and subtracted. One launch
// instead of two, no cross-block atomics on sums.
__global__ __launch_bounds__(64)
void reduce_mask_kernel(const float* __restrict__ sums_rep, const int* __restrict__ seq,
                        float* __restrict__ out, float* __restrict__ sums)
{
  const int b = blockIdx.x, t = threadIdx.x;   // 64 threads
  float s = sums_rep[(size_t)t * 256 + b];
  #pragma unroll
  for (int off = 32; off > 0; off >>= 1) s += __shfl_down(s, off, 64);

  float sub = 0.0f;
  if (t < L_) {
    const int item = seq[b * L_ + t];
    if (item > 0) {
      const float old = atomicExch(&out[(size_t)b * N_ + item], 0.0f);
      sub = old;   // duplicate items: only the first exch gets nonzero
    }
  }
  #pragma unroll
  for (int off = 32; off > 0; off >>= 1) sub += __shfl_down(sub, off, 64);

  if (t == 0) sums[b] = s - sub;
}

// ---------------- Kernel D: normalize (2D grid, no div, 4 float4/thread) ----------------
#define NV4 (N_ / 4)   // 25000 float4 per row
__global__ __launch_bounds__(256)
void norm_kernel(float* __restrict__ out, const float* __restrict__ sums)
{
  const int b = blockIdx.y;
  const float inv = 1.0f / sums[b];
  float4* row = (float4*)(out + (size_t)b * N_);
  const int i0 = blockIdx.x * (256 * 4) + threadIdx.x;
  #pragma unroll
  for (int u = 0; u < 4; ++u) {
    const int i = i0 + u * 256;
    if (i < NV4) {
      float4 v = row[i];
      v.x *= inv; v.y *= inv; v.z *= inv; v.w *= inv;
      row[i] = v;
    }
  }
}

extern "C" void kernel_launch(void* const* d_in, const int* in_sizes, int n_in,
                              void* d_out, int out_size, void* d_ws, size_t ws_size,
                              hipStream_t stream)
{
  const float* am   = (const float*)d_in[0];
  const float* lm   = (const float*)d_in[1];
  const int*   seq  = (const int*)d_in[2];
  const unsigned char* mask = (const unsigned char*)d_in[3];
  const float* Ue_w = (const float*)d_in[4];
  const float* Ue_b = (const float*)d_in[5];
  const float* We_w = (const float*)d_in[6];
  const float* We_b = (const float*)d_in[7];
  const float* Ve_w = (const float*)d_in[8];
  const float* Ve_b = (const float*)d_in[9];
  const float* Wexp = (const float*)d_in[10];
  float* out = (float*)d_out;

  short* feat_hi  = (short*)d_ws;                     // 128 KB
  short* feat_lo  = feat_hi + B_ * K_;                // 128 KB
  float* sums_rep = (float*)(feat_lo + B_ * K_);      // 64*256 floats = 64 KB
  float* sums     = sums_rep + NREP * 256;            // 256 floats

  attn_feat_kernel<<<B_, 256, 0, stream>>>(am, lm, Ue_w, Ue_b, We_w, We_b,
                                           Ve_w, Ve_b, mask, feat_hi, feat_lo, sums_rep);
  logits_mfma_kernel<<<GRIDB, 512, 0, stream>>>(feat_hi, feat_lo, Wexp, out, sums_rep);
  reduce_mask_kernel<<<B_, 64, 0, stream>>>(sums_rep, seq, out, sums);
  dim3 gN((NV4 + 256 * 4 - 1) / (256 * 4), B_);
  norm_kernel<<<gN, 256, 0, stream>>>(out, sums);
}